// Round 5
// baseline (368.284 us; speedup 1.0000x reference)
//
#include <hip/hip_runtime.h>
#include <cstddef>

// Problem constants
constexpr int B_ = 4, H_ = 96, W_ = 96, C_ = 192, QKVC = 576;
constexpr int NPIX = B_ * H_ * W_;           // 36864
constexpr float SCALE = 0.17677669529663689f; // 32^-0.5

typedef __attribute__((ext_vector_type(8))) short bf16x8;
typedef __attribute__((ext_vector_type(4))) float f32x4;
typedef unsigned short ushort_t;

__device__ __forceinline__ unsigned short f2bf(float f) {
    unsigned int u = __builtin_bit_cast(unsigned int, f);
    u += 0x7fffu + ((u >> 16) & 1u);       // round-to-nearest-even
    return (unsigned short)(u >> 16);
}
__device__ __forceinline__ float bf2f(unsigned short h) {
    unsigned int u = ((unsigned int)h) << 16;
    return __builtin_bit_cast(float, u);
}
__device__ __forceinline__ unsigned int pack2(unsigned short a, unsigned short b) {
    return (unsigned int)a | ((unsigned int)b << 16);
}

// ---------------------------------------------------------------------------
// convert_x: fp32 -> bf16, one float4 -> 8B per thread.
// ---------------------------------------------------------------------------
__global__ __launch_bounds__(256) void convert_x_kernel(
    const float* __restrict__ x, ushort_t* __restrict__ xh, int n4)
{
    int i = blockIdx.x * 256 + threadIdx.x;
    if (i >= n4) return;
    float4 v = ((const float4*)x)[i];
    uint2 p;
    p.x = pack2(f2bf(v.x), f2bf(v.y));
    p.y = pack2(f2bf(v.z), f2bf(v.w));
    ((uint2*)xh)[i] = p;
}

// ---------------------------------------------------------------------------
// convert_w: w_qkv[192][576] -> wqt[576][192] bf16;
//            w_proj[192][192] -> wpt_h/wpt_l[192][192] (split hi/lo bf16).
// ---------------------------------------------------------------------------
__global__ __launch_bounds__(256) void convert_w_kernel(
    const float* __restrict__ w_qkv, const float* __restrict__ w_proj,
    ushort_t* __restrict__ wqt, ushort_t* __restrict__ wpt_h,
    ushort_t* __restrict__ wpt_l)
{
    int idx = blockIdx.x * 256 + threadIdx.x;
    if (idx < 576 * 192) {
        int n = idx / 192, k = idx - n * 192;
        wqt[idx] = f2bf(w_qkv[(size_t)k * 576 + n]);
    } else {
        int i2 = idx - 576 * 192;
        if (i2 < 192 * 192) {
            int n = i2 / 192, k = i2 - n * 192;
            float v = w_proj[(size_t)k * 192 + n];
            unsigned short h = f2bf(v);
            wpt_h[i2] = h;
            wpt_l[i2] = f2bf(v - bf2f(h));
        }
    }
}

// ---------------------------------------------------------------------------
// MFMA bf16 GEMM, tile 64(M) x 192(N) x 64(K-step), 256 threads = 4 waves.
// A is bf16 [M][K]. B pre-transposed bf16 Bt[n][k].
// BSPLIT=false: 1 pass (A*Bh).  BSPLIT=true: 2 passes A*(Bh+Bl).
// LDS fragment-order with XOR swizzle: chunk(kc, i) at kc*DIM + (i ^ kc).
// ---------------------------------------------------------------------------
template<bool BSPLIT>
__global__ __launch_bounds__(256) void gemm_mfma2_kernel(
    const ushort_t* __restrict__ A,
    const ushort_t* __restrict__ Bt_h, const ushort_t* __restrict__ Bt_l,
    const float* __restrict__ bias, float* __restrict__ C,
    int M, int N, int K)
{
    constexpr int NPB = BSPLIT ? 2 : 1;
    __shared__ __align__(16) ushort_t As[8 * 64 * 8];
    __shared__ __align__(16) ushort_t Bs[NPB][8 * 192 * 8];

    const int tid = threadIdx.x;
    const int lane = tid & 63;
    const int w = tid >> 6;
    const int wm = (w & 1) * 32;
    const int wn = (w >> 1) * 96;
    const int fm = lane & 15;
    const int fq = lane >> 4;

    const int ntiles = N / 192;
    const int m0 = (blockIdx.x / ntiles) * 64;
    const int n0 = (blockIdx.x % ntiles) * 192;

    f32x4 acc[2][6];
    #pragma unroll
    for (int mi = 0; mi < 2; ++mi)
        #pragma unroll
        for (int ni = 0; ni < 6; ++ni)
            acc[mi][ni] = (f32x4){0.f, 0.f, 0.f, 0.f};

    for (int k0 = 0; k0 < K; k0 += 64) {
        __syncthreads();
        // ---- stage A (bf16 chunks) ----
        #pragma unroll
        for (int it = 0; it < 2; ++it) {
            int idx = it * 256 + tid;
            int m = idx >> 3, kc = idx & 7;
            uint4 v = *(const uint4*)(A + (size_t)(m0 + m) * K + k0 + kc * 8);
            *(uint4*)(&As[0] + (kc * 64 + (m ^ kc)) * 8) = v;
        }
        // ---- stage B ----
        #pragma unroll
        for (int it = 0; it < 6; ++it) {
            int idx = it * 256 + tid;
            int n = idx >> 3, kc = idx & 7;
            int phys = kc * 192 + (n ^ kc);
            *(uint4*)(&Bs[0][0] + phys * 8) =
                *(const uint4*)(Bt_h + (size_t)(n0 + n) * K + k0 + kc * 8);
            if constexpr (BSPLIT)
                *(uint4*)(&Bs[NPB - 1][0] + phys * 8) =
                    *(const uint4*)(Bt_l + (size_t)(n0 + n) * K + k0 + kc * 8);
        }
        __syncthreads();

        // ---- compute ----
        #pragma unroll
        for (int kt2 = 0; kt2 < 2; ++kt2) {
            const int kc = kt2 * 4 + fq;
            bf16x8 ah[2], bh[6];
            #pragma unroll
            for (int mi = 0; mi < 2; ++mi)
                ah[mi] = *(const bf16x8*)(&As[0] + (kc * 64 + ((wm + mi * 16 + fm) ^ kc)) * 8);
            #pragma unroll
            for (int ni = 0; ni < 6; ++ni)
                bh[ni] = *(const bf16x8*)(&Bs[0][0] + (kc * 192 + ((wn + ni * 16 + fm) ^ kc)) * 8);
            #pragma unroll
            for (int mi = 0; mi < 2; ++mi)
                #pragma unroll
                for (int ni = 0; ni < 6; ++ni)
                    acc[mi][ni] = __builtin_amdgcn_mfma_f32_16x16x32_bf16(
                        ah[mi], bh[ni], acc[mi][ni], 0, 0, 0);
            if constexpr (BSPLIT) {
                bf16x8 bl[6];
                #pragma unroll
                for (int ni = 0; ni < 6; ++ni)
                    bl[ni] = *(const bf16x8*)(&Bs[NPB - 1][0] + (kc * 192 + ((wn + ni * 16 + fm) ^ kc)) * 8);
                #pragma unroll
                for (int mi = 0; mi < 2; ++mi)
                    #pragma unroll
                    for (int ni = 0; ni < 6; ++ni)
                        acc[mi][ni] = __builtin_amdgcn_mfma_f32_16x16x32_bf16(
                            ah[mi], bl[ni], acc[mi][ni], 0, 0, 0);
            }
        }
    }

    // ---- epilogue: C/D layout col=lane&15, row=fq*4+reg ----
    #pragma unroll
    for (int ni = 0; ni < 6; ++ni) {
        const int col = n0 + wn + ni * 16 + fm;
        const float bv = bias[col];
        #pragma unroll
        for (int mi = 0; mi < 2; ++mi) {
            const int rbase = m0 + wm + mi * 16 + fq * 4;
            #pragma unroll
            for (int r = 0; r < 4; ++r)
                C[(size_t)(rbase + r) * N + col] = acc[mi][ni][r] + bv;
        }
    }
}

// ---------------------------------------------------------------------------
// Neighborhood attention, LDS-staged + register-prefetch pipeline.
// Physical blockIdx P is remapped so each XCD (P%8) owns 72 consecutive
// logical blocks (ip fastest within (g,b)) -> sliding k/v row window stays
// in the XCD's private L2.
// Per logical block (g,b,row-pair): 192 threads (j,h), each thread computes
// 2 pixels (rows i0,i1). Window rows staged one at a time into LDS; the NEXT
// row is prefetched into 16 VGPR float4s during compute, so the global-load
// latency is hidden by the VALU phase.
// Output attn is bf16.
// ---------------------------------------------------------------------------
__global__ __launch_bounds__(192) void na2d_kernel(
    const float* __restrict__ qkv, ushort_t* __restrict__ attn)
{
    __shared__ float4 smem[32 * 97];   // 49.7 KB: f=0..15 k (h0,h1), 16..31 v

    // XCD-locality remap: 576 = 8 XCDs x 72 consecutive logical blocks
    int P = blockIdx.x;
    int L = (P & 7) * 72 + (P >> 3);
    const int p  = L % 48;             // row-pair, fastest
    const int gb = L / 48;
    const int b  = gb & 3;
    const int g  = gb >> 2;

    const int i0 = 2 * p, i1 = i0 + 1;
    const int K = 7 + 2 * g;
    const int c = K >> 1;

    const int tid = threadIdx.x;
    const int j = tid % 96;
    const int h = tid / 96;
    const int h8 = h * 8;

    int si0 = i0 - c; if (si0 < 0) si0 = 0; if (si0 > H_ - K) si0 = H_ - K;
    int si1 = i1 - c; if (si1 < 0) si1 = 0; if (si1 > H_ - K) si1 = H_ - K;
    const int d01 = si1 - si0;
    const int nr = d01 + K;

    int sj = j - c; if (sj < 0) sj = 0; if (sj > W_ - K) sj = W_ - K;

    const float* q0p = qkv + (size_t)((b * H_ + i0) * W_ + j) * QKVC + g * 192 + h * 32;
    const float* q1p = q0p + (size_t)W_ * QKVC;
    float4 q0[8], q1[8], y0[8], y1[8];
    #pragma unroll
    for (int d4 = 0; d4 < 8; ++d4) {
        float4 t0 = ((const float4*)q0p)[d4];
        float4 t1 = ((const float4*)q1p)[d4];
        t0.x *= SCALE; t0.y *= SCALE; t0.z *= SCALE; t0.w *= SCALE;
        t1.x *= SCALE; t1.y *= SCALE; t1.z *= SCALE; t1.w *= SCALE;
        q0[d4] = t0; q1[d4] = t1;
        y0[d4] = make_float4(0.f, 0.f, 0.f, 0.f);
        y1[d4] = make_float4(0.f, 0.f, 0.f, 0.f);
    }
    float l0 = 0.f, l1 = 0.f;

    const float4* qkv4 = (const float4*)qkv;
    const int pix_s = tid >> 1;                 // staging: thread -> (pix, f-half)
    const int f_s   = (tid & 1) * 16;

    float4 pref[16];
    // prologue: prefetch first window row
    {
        const size_t rowbase = (size_t)(b * H_ + si0) * W_ * 144;
        #pragma unroll
        for (int it = 0; it < 16; ++it) {
            int idx = it * 192 + tid;
            int pix = idx >> 5, f = idx & 31;
            pref[it] = qkv4[rowbase + (size_t)pix * 144 + g * 48 + 16 + f];
        }
    }

    for (int t = 0; t < nr; ++t) {
        __syncthreads();   // previous iteration's readers done before overwrite
        #pragma unroll
        for (int it = 0; it < 16; ++it) {
            int idx = it * 192 + tid;
            int pix = idx >> 5, f = idx & 31;
            smem[f * 97 + pix] = pref[it];
        }
        __syncthreads();
        if (t + 1 < nr) {
            const size_t rowbase = (size_t)(b * H_ + si0 + t + 1) * W_ * 144;
            #pragma unroll
            for (int it = 0; it < 16; ++it) {
                int idx = it * 192 + tid;
                int pix = idx >> 5, f = idx & 31;
                pref[it] = qkv4[rowbase + (size_t)pix * 144 + g * 48 + 16 + f];
            }
        }

        const bool a0 = (t < K);
        const bool a1 = (t >= d01);
        for (int wj = 0; wj < K; ++wj) {
            const int col = sj + wj;
            float dot0 = 0.f, dot1 = 0.f;
            #pragma unroll
            for (int d4 = 0; d4 < 8; ++d4) {
                float4 kk = smem[(h8 + d4) * 97 + col];
                float4 a = q0[d4], bq = q1[d4];
                dot0 += a.x * kk.x + a.y * kk.y + a.z * kk.z + a.w * kk.w;
                dot1 += bq.x * kk.x + bq.y * kk.y + bq.z * kk.z + bq.w * kk.w;
            }
            const float e0 = a0 ? __expf(dot0) : 0.f;
            const float e1 = a1 ? __expf(dot1) : 0.f;
            l0 += e0; l1 += e1;
            #pragma unroll
            for (int d4 = 0; d4 < 8; ++d4) {
                float4 vv = smem[(16 + h8 + d4) * 97 + col];
                y0[d4].x += e0 * vv.x; y0[d4].y += e0 * vv.y;
                y0[d4].z += e0 * vv.z; y0[d4].w += e0 * vv.w;
                y1[d4].x += e1 * vv.x; y1[d4].y += e1 * vv.y;
                y1[d4].z += e1 * vv.z; y1[d4].w += e1 * vv.w;
            }
        }
    }

    const float inv0 = 1.f / l0, inv1 = 1.f / l1;
    ushort_t* o0 = attn + (size_t)((b * H_ + i0) * W_ + j) * C_ + g * 64 + h * 32;
    ushort_t* o1 = o0 + (size_t)W_ * C_;
    #pragma unroll
    for (int d4 = 0; d4 < 8; ++d4) {
        uint2 w0, w1;
        w0.x = pack2(f2bf(y0[d4].x * inv0), f2bf(y0[d4].y * inv0));
        w0.y = pack2(f2bf(y0[d4].z * inv0), f2bf(y0[d4].w * inv0));
        w1.x = pack2(f2bf(y1[d4].x * inv1), f2bf(y1[d4].y * inv1));
        w1.y = pack2(f2bf(y1[d4].z * inv1), f2bf(y1[d4].w * inv1));
        *(uint2*)(o0 + d4 * 4) = w0;
        *(uint2*)(o1 + d4 * 4) = w1;
    }
}

// ---------------------------------------------------------------------------
extern "C" void kernel_launch(void* const* d_in, const int* in_sizes, int n_in,
                              void* d_out, int out_size, void* d_ws, size_t ws_size,
                              hipStream_t stream)
{
    const float* x      = (const float*)d_in[0];
    const float* w_qkv  = (const float*)d_in[1];
    const float* b_qkv  = (const float*)d_in[2];
    const float* w_proj = (const float*)d_in[3];
    const float* b_proj = (const float*)d_in[4];
    float* out = (float*)d_out;

    // Workspace: [qkv fp32 84.93MB][xh/attn bf16 14.16MB (aliased)][weights]
    char* ws = (char*)d_ws;
    float*    qkv   = (float*)ws;
    char*     reg1  = ws + (size_t)NPIX * QKVC * 4;
    ushort_t* xh    = (ushort_t*)reg1;            // x bf16; dead after GEMM1
    ushort_t* attn  = (ushort_t*)reg1;            // attn bf16 (aliases xh)
    char*     wbase = reg1 + (size_t)NPIX * C_ * 2;
    ushort_t* wqt   = (ushort_t*)wbase;                        // 576x192 bf16
    ushort_t* wpt_h = (ushort_t*)(wbase + 576 * 192 * 2);      // 192x192 bf16
    ushort_t* wpt_l = (ushort_t*)(wbase + 576 * 192 * 2 + 192 * 192 * 2);

    // 0) conversions
    convert_x_kernel<<<(NPIX * C_ / 4 + 255) / 256, 256, 0, stream>>>(
        x, xh, NPIX * C_ / 4);
    convert_w_kernel<<<(576 * 192 + 192 * 192 + 255) / 256, 256, 0, stream>>>(
        w_qkv, w_proj, wqt, wpt_h, wpt_l);

    // 1) qkv = x @ w_qkv + b_qkv   (bf16 MFMA, 64x192 tiles)
    gemm_mfma2_kernel<false><<<(NPIX / 64) * (QKVC / 192), 256, 0, stream>>>(
        xh, wqt, nullptr, b_qkv, qkv, NPIX, QKVC, C_);

    // 2) neighborhood attention (bf16 out, aliases xh)
    na2d_kernel<<<576, 192, 0, stream>>>(qkv, attn);

    // 3) out = attn @ w_proj + b_proj  (A bf16, B split-bf16 2-pass MFMA)
    gemm_mfma2_kernel<true><<<(NPIX / 64) * (C_ / 192), 256, 0, stream>>>(
        attn, wpt_h, wpt_l, b_proj, out, NPIX, C_, C_);
}

// Round 6
// 232.900 us; speedup vs baseline: 1.5813x; 1.5813x over previous
//
#include <hip/hip_runtime.h>
#include <cstddef>

// Problem constants
constexpr int B_ = 4, H_ = 96, W_ = 96, C_ = 192, QKVC = 576;
constexpr int NPIX = B_ * H_ * W_;           // 36864
constexpr float SCALE = 0.17677669529663689f; // 32^-0.5

typedef __attribute__((ext_vector_type(8))) short bf16x8;
typedef __attribute__((ext_vector_type(4))) float f32x4;
typedef unsigned short ushort_t;

__device__ __forceinline__ unsigned short f2bf(float f) {
    unsigned int u = __builtin_bit_cast(unsigned int, f);
    u += 0x7fffu + ((u >> 16) & 1u);       // round-to-nearest-even
    return (unsigned short)(u >> 16);
}
__device__ __forceinline__ float bf2f(unsigned short h) {
    unsigned int u = ((unsigned int)h) << 16;
    return __builtin_bit_cast(float, u);
}
__device__ __forceinline__ unsigned int pack2(unsigned short a, unsigned short b) {
    return (unsigned int)a | ((unsigned int)b << 16);
}
// unpack the two bf16 halves of a dword to fp32
__device__ __forceinline__ float bflo(unsigned int u) {
    return __builtin_bit_cast(float, u << 16);
}
__device__ __forceinline__ float bfhi(unsigned int u) {
    return __builtin_bit_cast(float, u & 0xffff0000u);
}

// ---------------------------------------------------------------------------
// convert_x: fp32 -> bf16, one float4 -> 8B per thread.
// ---------------------------------------------------------------------------
__global__ __launch_bounds__(256) void convert_x_kernel(
    const float* __restrict__ x, ushort_t* __restrict__ xh, int n4)
{
    int i = blockIdx.x * 256 + threadIdx.x;
    if (i >= n4) return;
    float4 v = ((const float4*)x)[i];
    uint2 p;
    p.x = pack2(f2bf(v.x), f2bf(v.y));
    p.y = pack2(f2bf(v.z), f2bf(v.w));
    ((uint2*)xh)[i] = p;
}

// ---------------------------------------------------------------------------
// convert_w: w_qkv[192][576] -> wqt[576][192] bf16;
//            w_proj[192][192] -> wpt_h/wpt_l[192][192] (split hi/lo bf16).
// ---------------------------------------------------------------------------
__global__ __launch_bounds__(256) void convert_w_kernel(
    const float* __restrict__ w_qkv, const float* __restrict__ w_proj,
    ushort_t* __restrict__ wqt, ushort_t* __restrict__ wpt_h,
    ushort_t* __restrict__ wpt_l)
{
    int idx = blockIdx.x * 256 + threadIdx.x;
    if (idx < 576 * 192) {
        int n = idx / 192, k = idx - n * 192;
        wqt[idx] = f2bf(w_qkv[(size_t)k * 576 + n]);
    } else {
        int i2 = idx - 576 * 192;
        if (i2 < 192 * 192) {
            int n = i2 / 192, k = i2 - n * 192;
            float v = w_proj[(size_t)k * 192 + n];
            unsigned short h = f2bf(v);
            wpt_h[i2] = h;
            wpt_l[i2] = f2bf(v - bf2f(h));
        }
    }
}

// ---------------------------------------------------------------------------
// MFMA bf16 GEMM, tile 64(M) x 192(N) x 64(K-step), 256 threads = 4 waves.
// A is bf16 [M][K]. B pre-transposed bf16 Bt[n][k].
// BSPLIT=false: 1 pass (A*Bh).  BSPLIT=true: 2 passes A*(Bh+Bl).
// OUTBF: store C as bf16 instead of fp32.
// LDS fragment-order with XOR swizzle: chunk(kc, i) at kc*DIM + (i ^ kc).
// ---------------------------------------------------------------------------
template<bool BSPLIT, bool OUTBF>
__global__ __launch_bounds__(256) void gemm_mfma2_kernel(
    const ushort_t* __restrict__ A,
    const ushort_t* __restrict__ Bt_h, const ushort_t* __restrict__ Bt_l,
    const float* __restrict__ bias, void* __restrict__ Cout,
    int M, int N, int K)
{
    constexpr int NPB = BSPLIT ? 2 : 1;
    __shared__ __align__(16) ushort_t As[8 * 64 * 8];
    __shared__ __align__(16) ushort_t Bs[NPB][8 * 192 * 8];

    const int tid = threadIdx.x;
    const int lane = tid & 63;
    const int w = tid >> 6;
    const int wm = (w & 1) * 32;
    const int wn = (w >> 1) * 96;
    const int fm = lane & 15;
    const int fq = lane >> 4;

    const int ntiles = N / 192;
    const int m0 = (blockIdx.x / ntiles) * 64;
    const int n0 = (blockIdx.x % ntiles) * 192;

    f32x4 acc[2][6];
    #pragma unroll
    for (int mi = 0; mi < 2; ++mi)
        #pragma unroll
        for (int ni = 0; ni < 6; ++ni)
            acc[mi][ni] = (f32x4){0.f, 0.f, 0.f, 0.f};

    for (int k0 = 0; k0 < K; k0 += 64) {
        __syncthreads();
        // ---- stage A (bf16 chunks) ----
        #pragma unroll
        for (int it = 0; it < 2; ++it) {
            int idx = it * 256 + tid;
            int m = idx >> 3, kc = idx & 7;
            uint4 v = *(const uint4*)(A + (size_t)(m0 + m) * K + k0 + kc * 8);
            *(uint4*)(&As[0] + (kc * 64 + (m ^ kc)) * 8) = v;
        }
        // ---- stage B ----
        #pragma unroll
        for (int it = 0; it < 6; ++it) {
            int idx = it * 256 + tid;
            int n = idx >> 3, kc = idx & 7;
            int phys = kc * 192 + (n ^ kc);
            *(uint4*)(&Bs[0][0] + phys * 8) =
                *(const uint4*)(Bt_h + (size_t)(n0 + n) * K + k0 + kc * 8);
            if constexpr (BSPLIT)
                *(uint4*)(&Bs[NPB - 1][0] + phys * 8) =
                    *(const uint4*)(Bt_l + (size_t)(n0 + n) * K + k0 + kc * 8);
        }
        __syncthreads();

        // ---- compute ----
        #pragma unroll
        for (int kt2 = 0; kt2 < 2; ++kt2) {
            const int kc = kt2 * 4 + fq;
            bf16x8 ah[2], bh[6];
            #pragma unroll
            for (int mi = 0; mi < 2; ++mi)
                ah[mi] = *(const bf16x8*)(&As[0] + (kc * 64 + ((wm + mi * 16 + fm) ^ kc)) * 8);
            #pragma unroll
            for (int ni = 0; ni < 6; ++ni)
                bh[ni] = *(const bf16x8*)(&Bs[0][0] + (kc * 192 + ((wn + ni * 16 + fm) ^ kc)) * 8);
            #pragma unroll
            for (int mi = 0; mi < 2; ++mi)
                #pragma unroll
                for (int ni = 0; ni < 6; ++ni)
                    acc[mi][ni] = __builtin_amdgcn_mfma_f32_16x16x32_bf16(
                        ah[mi], bh[ni], acc[mi][ni], 0, 0, 0);
            if constexpr (BSPLIT) {
                bf16x8 bl[6];
                #pragma unroll
                for (int ni = 0; ni < 6; ++ni)
                    bl[ni] = *(const bf16x8*)(&Bs[NPB - 1][0] + (kc * 192 + ((wn + ni * 16 + fm) ^ kc)) * 8);
                #pragma unroll
                for (int mi = 0; mi < 2; ++mi)
                    #pragma unroll
                    for (int ni = 0; ni < 6; ++ni)
                        acc[mi][ni] = __builtin_amdgcn_mfma_f32_16x16x32_bf16(
                            ah[mi], bl[ni], acc[mi][ni], 0, 0, 0);
            }
        }
    }

    // ---- epilogue: C/D layout col=lane&15, row=fq*4+reg ----
    #pragma unroll
    for (int ni = 0; ni < 6; ++ni) {
        const int col = n0 + wn + ni * 16 + fm;
        const float bv = bias[col];
        #pragma unroll
        for (int mi = 0; mi < 2; ++mi) {
            const int rbase = m0 + wm + mi * 16 + fq * 4;
            #pragma unroll
            for (int r = 0; r < 4; ++r) {
                if constexpr (OUTBF)
                    ((ushort_t*)Cout)[(size_t)(rbase + r) * N + col] =
                        f2bf(acc[mi][ni][r] + bv);
                else
                    ((float*)Cout)[(size_t)(rbase + r) * N + col] =
                        acc[mi][ni][r] + bv;
            }
        }
    }
}

// ---------------------------------------------------------------------------
// Neighborhood attention v3: bf16 qkv, async LDS double-buffer staging.
// Block = (g, h, b, row-pair): 1152 blocks, 192 threads (j in 0..95, row
// i0 or i0+1). One pixel per thread (head h fixed per block).
// LDS: 2 buffers x [16 chunks][96 pix] x 16B (chunk = 8 bf16 ch of k then v
// for head h) = 2 x 12 KB. Next window row streamed into the idle buffer
// with global_load_lds (wave-uniform LDS base + lane*16) during compute.
// Balanced XCD remap: XCD x gets 24 consecutive row-pair blocks of EVERY
// (g,h) (groups interleaved in dispatch order -> no inter-XCD skew).
// ---------------------------------------------------------------------------
__global__ __launch_bounds__(192, 1) void na2d_kernel(
    const ushort_t* __restrict__ qkv, ushort_t* __restrict__ attn)
{
    __shared__ uint4 smem[2][768];   // 2 x (8 chunks x 96 pix) x 16B

    const int x = blockIdx.x & 7;        // XCD (heuristic P%8)
    const int s = blockIdx.x >> 3;       // 0..143
    const int gh = s % 6;
    const int c24 = s / 6;               // 0..23 consecutive pair-chunk
    const int g = gh >> 1, h = gh & 1;
    const int idx = x * 24 + c24;        // 0..191
    const int b = idx / 48, p = idx % 48;

    const int K = 7 + 2 * g;
    const int cc = K >> 1;
    const int i0 = 2 * p;

    const int tid = threadIdx.x;
    const int rsel = tid / 96;           // which row of the pair
    const int j = tid % 96;
    const int i = i0 + rsel;

    int si0 = i0 - cc;     if (si0 < 0) si0 = 0; if (si0 > H_ - K) si0 = H_ - K;
    int si1 = i0 + 1 - cc; if (si1 < 0) si1 = 0; if (si1 > H_ - K) si1 = H_ - K;
    const int d01 = si1 - si0;           // 0 or 1
    const int nr = d01 + K;              // staged rows
    const int tlo = rsel ? d01 : 0;      // this thread's active t range
    const int thi = rsel ? nr : K;

    int sj = j - cc; if (sj < 0) sj = 0; if (sj > W_ - K) sj = W_ - K;

    // per-lane global byte offsets for the 4 staging slots of this lane
    const int lane = tid & 63, wv = tid >> 6;
    int goffs[4];
    #pragma unroll
    for (int s8 = 0; s8 < 4; ++s8) {
        int flat = wv * 256 + s8 * 64 + lane;    // slot = chunk*96 + pix
        int chunk = flat / 96, pix = flat - chunk * 96;
        // k chunks 0..3 at ch 64+c*8, v chunks 4..7 at ch 128+(c-4)*8 (head h)
        int offu = pix * QKVC + g * 192 + 64 + ((chunk >> 2) << 6) + h * 32 + (chunk & 3) * 8;
        goffs[s8] = offu * 2;
    }
    const char* qbytes = (const char*)qkv;

    // q for this pixel (bf16 -> fp32, scaled)
    const ushort_t* qp = qkv + (size_t)((b * H_ + i) * W_ + j) * QKVC + g * 192 + h * 32;
    float4 q[8], y[8];
    #pragma unroll
    for (int d2 = 0; d2 < 4; ++d2) {
        uint4 u = ((const uint4*)qp)[d2];
        q[d2 * 2 + 0] = make_float4(bflo(u.x) * SCALE, bfhi(u.x) * SCALE,
                                    bflo(u.y) * SCALE, bfhi(u.y) * SCALE);
        q[d2 * 2 + 1] = make_float4(bflo(u.z) * SCALE, bfhi(u.z) * SCALE,
                                    bflo(u.w) * SCALE, bfhi(u.w) * SCALE);
    }
    #pragma unroll
    for (int d = 0; d < 8; ++d) y[d] = make_float4(0.f, 0.f, 0.f, 0.f);
    float l = 0.f;

    // prologue: stream window row si0 into buffer 0
    {
        const char* rowb = qbytes + (size_t)((b * H_ + si0) * W_) * (QKVC * 2);
        #pragma unroll
        for (int s8 = 0; s8 < 4; ++s8)
            __builtin_amdgcn_global_load_lds(
                (const __attribute__((address_space(1))) void*)(rowb + goffs[s8]),
                (__attribute__((address_space(3))) void*)(&smem[0][0] + wv * 256 + s8 * 64),
                16, 0, 0);
    }

    for (int t = 0; t < nr; ++t) {
        __syncthreads();   // drains vmcnt: buf[t&1] ready; prior readers done
        if (t + 1 < nr) {
            const char* rowb = qbytes + (size_t)((b * H_ + si0 + t + 1) * W_) * (QKVC * 2);
            uint4* dst = &smem[(t + 1) & 1][0];
            #pragma unroll
            for (int s8 = 0; s8 < 4; ++s8)
                __builtin_amdgcn_global_load_lds(
                    (const __attribute__((address_space(1))) void*)(rowb + goffs[s8]),
                    (__attribute__((address_space(3))) void*)(dst + wv * 256 + s8 * 64),
                    16, 0, 0);
        }
        if (t >= tlo && t < thi) {
            const uint4* buf = &smem[t & 1][0];
            for (int wj = 0; wj < K; ++wj) {
                const int col = sj + wj;
                const uint4* kc = buf + col;
                float dot = 0.f;
                #pragma unroll
                for (int d4 = 0; d4 < 4; ++d4) {
                    uint4 u = kc[d4 * 96];
                    float4 qa = q[d4 * 2], qb = q[d4 * 2 + 1];
                    dot += qa.x * bflo(u.x) + qa.y * bfhi(u.x)
                         + qa.z * bflo(u.y) + qa.w * bfhi(u.y);
                    dot += qb.x * bflo(u.z) + qb.y * bfhi(u.z)
                         + qb.z * bflo(u.w) + qb.w * bfhi(u.w);
                }
                const float e = __expf(dot);
                l += e;
                #pragma unroll
                for (int d4 = 0; d4 < 4; ++d4) {
                    uint4 u = kc[(4 + d4) * 96];
                    y[d4 * 2].x     += e * bflo(u.x);
                    y[d4 * 2].y     += e * bfhi(u.x);
                    y[d4 * 2].z     += e * bflo(u.y);
                    y[d4 * 2].w     += e * bfhi(u.y);
                    y[d4 * 2 + 1].x += e * bflo(u.z);
                    y[d4 * 2 + 1].y += e * bfhi(u.z);
                    y[d4 * 2 + 1].z += e * bflo(u.w);
                    y[d4 * 2 + 1].w += e * bfhi(u.w);
                }
            }
        }
    }

    const float inv = 1.f / l;
    ushort_t* op = attn + (size_t)((b * H_ + i) * W_ + j) * C_ + g * 64 + h * 32;
    #pragma unroll
    for (int d2 = 0; d2 < 4; ++d2) {
        float4 a = y[d2 * 2], c = y[d2 * 2 + 1];
        uint4 wo;
        wo.x = pack2(f2bf(a.x * inv), f2bf(a.y * inv));
        wo.y = pack2(f2bf(a.z * inv), f2bf(a.w * inv));
        wo.z = pack2(f2bf(c.x * inv), f2bf(c.y * inv));
        wo.w = pack2(f2bf(c.z * inv), f2bf(c.w * inv));
        ((uint4*)op)[d2] = wo;
    }
}

// ---------------------------------------------------------------------------
extern "C" void kernel_launch(void* const* d_in, const int* in_sizes, int n_in,
                              void* d_out, int out_size, void* d_ws, size_t ws_size,
                              hipStream_t stream)
{
    const float* x      = (const float*)d_in[0];
    const float* w_qkv  = (const float*)d_in[1];
    const float* b_qkv  = (const float*)d_in[2];
    const float* w_proj = (const float*)d_in[3];
    const float* b_proj = (const float*)d_in[4];
    float* out = (float*)d_out;

    // Workspace: [qkv bf16 42.5MB][xh/attn bf16 14.2MB (aliased)][weights]
    char* ws = (char*)d_ws;
    ushort_t* qkvh  = (ushort_t*)ws;
    char*     reg1  = ws + (size_t)NPIX * QKVC * 2;
    ushort_t* xh    = (ushort_t*)reg1;            // x bf16; dead after GEMM1
    ushort_t* attn  = (ushort_t*)reg1;            // attn bf16 (aliases xh)
    char*     wbase = reg1 + (size_t)NPIX * C_ * 2;
    ushort_t* wqt   = (ushort_t*)wbase;                        // 576x192 bf16
    ushort_t* wpt_h = (ushort_t*)(wbase + 576 * 192 * 2);      // 192x192 bf16
    ushort_t* wpt_l = (ushort_t*)(wbase + 576 * 192 * 2 + 192 * 192 * 2);

    // 0) conversions
    convert_x_kernel<<<(NPIX * C_ / 4 + 255) / 256, 256, 0, stream>>>(
        x, xh, NPIX * C_ / 4);
    convert_w_kernel<<<(576 * 192 + 192 * 192 + 255) / 256, 256, 0, stream>>>(
        w_qkv, w_proj, wqt, wpt_h, wpt_l);

    // 1) qkv = x @ w_qkv + b_qkv   (bf16 MFMA, bf16 output)
    gemm_mfma2_kernel<false, true><<<(NPIX / 64) * (QKVC / 192), 256, 0, stream>>>(
        xh, wqt, nullptr, b_qkv, qkvh, NPIX, QKVC, C_);

    // 2) neighborhood attention (bf16 in/out): 8 XCD x 144 blocks
    na2d_kernel<<<1152, 192, 0, stream>>>(qkvh, attn);

    // 3) out = attn @ w_proj + b_proj  (A bf16, B split-bf16 2-pass, fp32 out)
    gemm_mfma2_kernel<true, false><<<(NPIX / 64) * (C_ / 192), 256, 0, stream>>>(
        attn, wpt_h, wpt_l, b_proj, out, NPIX, C_, C_);
}

// Round 7
// 187.097 us; speedup vs baseline: 1.9684x; 1.2448x over previous
//
#include <hip/hip_runtime.h>
#include <cstddef>

// Problem constants
constexpr int B_ = 4, H_ = 96, W_ = 96, C_ = 192, QKVC = 576;
constexpr int NPIX = B_ * H_ * W_;           // 36864
constexpr float SCALE = 0.17677669529663689f; // 32^-0.5

typedef __attribute__((ext_vector_type(8))) short bf16x8;
typedef __attribute__((ext_vector_type(4))) float f32x4;
typedef unsigned short ushort_t;

__device__ __forceinline__ unsigned short f2bf(float f) {
    unsigned int u = __builtin_bit_cast(unsigned int, f);
    u += 0x7fffu + ((u >> 16) & 1u);       // round-to-nearest-even
    return (unsigned short)(u >> 16);
}
__device__ __forceinline__ float bf2f(unsigned short h) {
    unsigned int u = ((unsigned int)h) << 16;
    return __builtin_bit_cast(float, u);
}
__device__ __forceinline__ unsigned int pack2(unsigned short a, unsigned short b) {
    return (unsigned int)a | ((unsigned int)b << 16);
}

// ---------------------------------------------------------------------------
// convert_x: fp32 -> bf16
// ---------------------------------------------------------------------------
__global__ __launch_bounds__(256) void convert_x_kernel(
    const float* __restrict__ x, ushort_t* __restrict__ xh, int n4)
{
    int i = blockIdx.x * 256 + threadIdx.x;
    if (i >= n4) return;
    float4 v = ((const float4*)x)[i];
    uint2 p;
    p.x = pack2(f2bf(v.x), f2bf(v.y));
    p.y = pack2(f2bf(v.z), f2bf(v.w));
    ((uint2*)xh)[i] = p;
}

// ---------------------------------------------------------------------------
// convert_w: w_qkv -> wqt[576][192] bf16; w_proj -> wpt_h/wpt_l split bf16.
// ---------------------------------------------------------------------------
__global__ __launch_bounds__(256) void convert_w_kernel(
    const float* __restrict__ w_qkv, const float* __restrict__ w_proj,
    ushort_t* __restrict__ wqt, ushort_t* __restrict__ wpt_h,
    ushort_t* __restrict__ wpt_l)
{
    int idx = blockIdx.x * 256 + threadIdx.x;
    if (idx < 576 * 192) {
        int n = idx / 192, k = idx - n * 192;
        wqt[idx] = f2bf(w_qkv[(size_t)k * 576 + n]);
    } else {
        int i2 = idx - 576 * 192;
        if (i2 < 192 * 192) {
            int n = i2 / 192, k = i2 - n * 192;
            float v = w_proj[(size_t)k * 192 + n];
            unsigned short h = f2bf(v);
            wpt_h[i2] = h;
            wpt_l[i2] = f2bf(v - bf2f(h));
        }
    }
}

// ---------------------------------------------------------------------------
// MFMA bf16 GEMM, tile 64x192x64. A bf16 [M][K], B pre-transposed Bt[n][k].
// BSPLIT: 2 passes A*(Bh+Bl). OUTBF: bf16 C. VT: additionally write the
// v-channels (local col 128..191) transposed to vT[b,i,g,h][32d][96j] bf16.
// ---------------------------------------------------------------------------
template<bool BSPLIT, bool OUTBF, bool VT>
__global__ __launch_bounds__(256) void gemm_mfma2_kernel(
    const ushort_t* __restrict__ A,
    const ushort_t* __restrict__ Bt_h, const ushort_t* __restrict__ Bt_l,
    const float* __restrict__ bias, void* __restrict__ Cout,
    ushort_t* __restrict__ vTout, int M, int N, int K)
{
    constexpr int NPB = BSPLIT ? 2 : 1;
    __shared__ __align__(16) ushort_t As[8 * 64 * 8];
    __shared__ __align__(16) ushort_t Bs[NPB][8 * 192 * 8];

    const int tid = threadIdx.x;
    const int lane = tid & 63;
    const int w = tid >> 6;
    const int wm = (w & 1) * 32;
    const int wn = (w >> 1) * 96;
    const int fm = lane & 15;
    const int fq = lane >> 4;

    const int ntiles = N / 192;
    const int m0 = (blockIdx.x / ntiles) * 64;
    const int n0 = (blockIdx.x % ntiles) * 192;

    f32x4 acc[2][6];
    #pragma unroll
    for (int mi = 0; mi < 2; ++mi)
        #pragma unroll
        for (int ni = 0; ni < 6; ++ni)
            acc[mi][ni] = (f32x4){0.f, 0.f, 0.f, 0.f};

    for (int k0 = 0; k0 < K; k0 += 64) {
        __syncthreads();
        #pragma unroll
        for (int it = 0; it < 2; ++it) {
            int idx = it * 256 + tid;
            int m = idx >> 3, kc = idx & 7;
            uint4 v = *(const uint4*)(A + (size_t)(m0 + m) * K + k0 + kc * 8);
            *(uint4*)(&As[0] + (kc * 64 + (m ^ kc)) * 8) = v;
        }
        #pragma unroll
        for (int it = 0; it < 6; ++it) {
            int idx = it * 256 + tid;
            int n = idx >> 3, kc = idx & 7;
            int phys = kc * 192 + (n ^ kc);
            *(uint4*)(&Bs[0][0] + phys * 8) =
                *(const uint4*)(Bt_h + (size_t)(n0 + n) * K + k0 + kc * 8);
            if constexpr (BSPLIT)
                *(uint4*)(&Bs[NPB - 1][0] + phys * 8) =
                    *(const uint4*)(Bt_l + (size_t)(n0 + n) * K + k0 + kc * 8);
        }
        __syncthreads();

        #pragma unroll
        for (int kt2 = 0; kt2 < 2; ++kt2) {
            const int kc = kt2 * 4 + fq;
            bf16x8 ah[2], bh[6];
            #pragma unroll
            for (int mi = 0; mi < 2; ++mi)
                ah[mi] = *(const bf16x8*)(&As[0] + (kc * 64 + ((wm + mi * 16 + fm) ^ kc)) * 8);
            #pragma unroll
            for (int ni = 0; ni < 6; ++ni)
                bh[ni] = *(const bf16x8*)(&Bs[0][0] + (kc * 192 + ((wn + ni * 16 + fm) ^ kc)) * 8);
            #pragma unroll
            for (int mi = 0; mi < 2; ++mi)
                #pragma unroll
                for (int ni = 0; ni < 6; ++ni)
                    acc[mi][ni] = __builtin_amdgcn_mfma_f32_16x16x32_bf16(
                        ah[mi], bh[ni], acc[mi][ni], 0, 0, 0);
            if constexpr (BSPLIT) {
                bf16x8 bl[6];
                #pragma unroll
                for (int ni = 0; ni < 6; ++ni)
                    bl[ni] = *(const bf16x8*)(&Bs[NPB - 1][0] + (kc * 192 + ((wn + ni * 16 + fm) ^ kc)) * 8);
                #pragma unroll
                for (int mi = 0; mi < 2; ++mi)
                    #pragma unroll
                    for (int ni = 0; ni < 6; ++ni)
                        acc[mi][ni] = __builtin_amdgcn_mfma_f32_16x16x32_bf16(
                            ah[mi], bl[ni], acc[mi][ni], 0, 0, 0);
            }
        }
    }

    // epilogue: C/D col=lane&15, row=fq*4+reg
    #pragma unroll
    for (int ni = 0; ni < 6; ++ni) {
        const int lcol = wn + ni * 16 + fm;
        const int col = n0 + lcol;
        const float bv = bias[col];
        const int vl = lcol - 128;               // v-channel index (if >=0)
        #pragma unroll
        for (int mi = 0; mi < 2; ++mi) {
            const int rbase = m0 + wm + mi * 16 + fq * 4;
            #pragma unroll
            for (int r = 0; r < 4; ++r) {
                float val = acc[mi][ni][r] + bv;
                if constexpr (OUTBF)
                    ((ushort_t*)Cout)[(size_t)(rbase + r) * N + col] = f2bf(val);
                else
                    ((float*)Cout)[(size_t)(rbase + r) * N + col] = val;
                if constexpr (VT) {
                    if (vl >= 0) {
                        int pix = rbase + r;
                        int bb = pix / 9216;
                        int rem = pix - bb * 9216;
                        int ii = rem / 96;
                        int jj = rem - ii * 96;
                        int hh = vl >> 5, dd = vl & 31;
                        vTout[((size_t)((bb * 96 + ii) * 6) + (n0 / 192) * 2 + hh) * 3072
                              + dd * 96 + jj] = f2bf(val);
                    }
                }
            }
        }
    }
}

// ---------------------------------------------------------------------------
// Neighborhood attention v4 — MFMA flash-style.
// Block = (g, h, b, row i): 2304 blocks, 384 threads = 6 waves; wave c owns
// the 16-pixel chunk j in [16c, 16c+16). Per window row t (K of them):
//   S[16x32] = Q·K^T via 2x mfma_16x16x32_bf16 over the chunk's 32-col
//   union window (cb multiple of 8); mask invalid cols, e=exp(S*SCALE);
//   P through per-wave LDS (C-layout -> A-layout); y += P·V via 2x mfma
//   with B-frags from Vt (dim-major V, precomputed by GEMM1's epilogue).
// K/Vt staged double-buffered with register prefetch (2 uint4/thread).
// l accumulated from bf16-rounded P (numerator-consistent), reduced with
// 4x shfl_xor over the 16 col-lanes.
// ---------------------------------------------------------------------------
__global__ __launch_bounds__(384, 5) void na2d_kernel(
    const ushort_t* __restrict__ qkv, const ushort_t* __restrict__ vT,
    ushort_t* __restrict__ attn)
{
    __shared__ ushort_t Kb[2][96 * 40];    // [col][pad40], chunk-XOR swizzle
    __shared__ ushort_t Vtb[2][32 * 104];  // [dim][pad104]
    __shared__ ushort_t Pb[6][16 * 40];    // per-wave P, [pix][pad40] swizzled

    int idx = blockIdx.x;
    const int g = idx % 3; idx /= 3;       // g fastest: XCD load balance
    const int h = idx & 1; idx >>= 1;
    const int i = idx % 96;
    const int b = idx / 96;

    const int K = 7 + 2 * g, cc = K >> 1;
    int si = i - cc; if (si < 0) si = 0; if (si > H_ - K) si = H_ - K;

    const int tid = threadIdx.x;
    const int w = tid >> 6, lane = tid & 63;
    const int fm = lane & 15, fq = lane >> 4;
    const int pixbase = w * 16;

    int cb = (pixbase - cc) & ~7;          // aligned union-window base
    if (cb < 0) cb = 0; if (cb > 64) cb = 64;
    const int col0 = cb + fm, col1 = cb + 16 + fm;

    int sj[4];
    #pragma unroll
    for (int r = 0; r < 4; ++r) {
        int jj = pixbase + fq * 4 + r - cc;
        if (jj < 0) jj = 0; if (jj > W_ - K) jj = W_ - K;
        sj[r] = jj;
    }

    // Q A-frag: pixel j=pixbase+fm, dims fq*8..+8
    const size_t rowstride = (size_t)W_ * QKVC;    // ushorts per image row
    const bf16x8 qfrag = *(const bf16x8*)(
        qkv + (size_t)(b * H_ + i) * rowstride + (size_t)(pixbase + fm) * QKVC
        + g * 192 + h * 32 + fq * 8);

    // staging maps (coalesced: addr = base + tid*16B for both)
    const int scol = tid >> 2, sch = tid & 3;
    const size_t kgoff = (size_t)scol * QKVC + g * 192 + 64 + h * 32 + sch * 8;
    const int klds = scol * 40 + ((sch ^ (scol & 3)) << 3);
    const int vd = tid / 12, vc8 = tid - vd * 12;
    const int vlds = vd * 104 + vc8 * 8;
    const size_t vslice = ((size_t)((b * H_ + si) * 6) + g * 2 + h) * 3072;

    f32x4 y0 = {0.f, 0.f, 0.f, 0.f}, y1 = {0.f, 0.f, 0.f, 0.f};
    float lacc[4] = {0.f, 0.f, 0.f, 0.f};

    uint4 kv = *(const uint4*)(qkv + (size_t)(b * H_ + si) * rowstride + kgoff);
    uint4 vv = *(const uint4*)(vT + vslice + (size_t)tid * 8);

    for (int t = 0; t < K; ++t) {
        *(uint4*)&Kb[t & 1][klds] = kv;
        *(uint4*)&Vtb[t & 1][vlds] = vv;
        if (t + 1 < K) {
            kv = *(const uint4*)(qkv + (size_t)(b * H_ + si + t + 1) * rowstride + kgoff);
            vv = *(const uint4*)(vT + vslice + (size_t)(t + 1) * 18432 + (size_t)tid * 8);
        }
        __syncthreads();

        // ---- S = Q·K^T (2 col-tiles) ----
        bf16x8 kf0 = *(const bf16x8*)&Kb[t & 1][col0 * 40 + ((fq ^ (col0 & 3)) << 3)];
        bf16x8 kf1 = *(const bf16x8*)&Kb[t & 1][col1 * 40 + ((fq ^ (col1 & 3)) << 3)];
        f32x4 s0 = __builtin_amdgcn_mfma_f32_16x16x32_bf16(
            qfrag, kf0, (f32x4){0.f, 0.f, 0.f, 0.f}, 0, 0, 0);
        f32x4 s1 = __builtin_amdgcn_mfma_f32_16x16x32_bf16(
            qfrag, kf1, (f32x4){0.f, 0.f, 0.f, 0.f}, 0, 0, 0);

        // ---- mask, exp, P write (C-layout -> LDS in A-frag order) ----
        #pragma unroll
        for (int r = 0; r < 4; ++r) {
            float e0 = __expf(s0[r] * SCALE);
            float e1 = __expf(s1[r] * SCALE);
            e0 = ((unsigned)(col0 - sj[r]) < (unsigned)K) ? e0 : 0.f;
            e1 = ((unsigned)(col1 - sj[r]) < (unsigned)K) ? e1 : 0.f;
            unsigned short p0 = f2bf(e0), p1 = f2bf(e1);
            lacc[r] += bf2f(p0) + bf2f(p1);
            const int m = fq * 4 + r;
            Pb[w][m * 40 + (((fm >> 3) ^ (m & 3)) << 3) + (fm & 7)] = p0;
            Pb[w][m * 40 + ((((fm >> 3) + 2) ^ (m & 3)) << 3) + (fm & 7)] = p1;
        }

        // ---- y += P·V (2 dim-tiles) ----
        bf16x8 pf = *(const bf16x8*)&Pb[w][fm * 40 + ((fq ^ (fm & 3)) << 3)];
        bf16x8 vf0 = *(const bf16x8*)&Vtb[t & 1][fm * 104 + cb + fq * 8];
        bf16x8 vf1 = *(const bf16x8*)&Vtb[t & 1][(16 + fm) * 104 + cb + fq * 8];
        y0 = __builtin_amdgcn_mfma_f32_16x16x32_bf16(pf, vf0, y0, 0, 0, 0);
        y1 = __builtin_amdgcn_mfma_f32_16x16x32_bf16(pf, vf1, y1, 0, 0, 0);
    }

    // ---- l reduce over the 16 col-lanes, normalize, store bf16 ----
    #pragma unroll
    for (int r = 0; r < 4; ++r) {
        float l = lacc[r];
        l += __shfl_xor(l, 1); l += __shfl_xor(l, 2);
        l += __shfl_xor(l, 4); l += __shfl_xor(l, 8);
        const float inv = 1.f / l;
        const int j = pixbase + fq * 4 + r;
        const size_t o = (size_t)((b * H_ + i) * W_ + j) * C_ + g * 64 + h * 32 + fm;
        attn[o]      = f2bf(y0[r] * inv);
        attn[o + 16] = f2bf(y1[r] * inv);
    }
}

// ---------------------------------------------------------------------------
extern "C" void kernel_launch(void* const* d_in, const int* in_sizes, int n_in,
                              void* d_out, int out_size, void* d_ws, size_t ws_size,
                              hipStream_t stream)
{
    const float* x      = (const float*)d_in[0];
    const float* w_qkv  = (const float*)d_in[1];
    const float* b_qkv  = (const float*)d_in[2];
    const float* w_proj = (const float*)d_in[3];
    const float* b_proj = (const float*)d_in[4];
    float* out = (float*)d_out;

    // Workspace: [qkvh 42.5MB][xh/attn bf16 14.2MB aliased][weights][vT 14.2MB]
    char* ws = (char*)d_ws;
    ushort_t* qkvh  = (ushort_t*)ws;
    char*     reg1  = ws + (size_t)NPIX * QKVC * 2;
    ushort_t* xh    = (ushort_t*)reg1;            // dead after GEMM1
    ushort_t* attn  = (ushort_t*)reg1;            // aliases xh
    char*     wbase = reg1 + (size_t)NPIX * C_ * 2;
    ushort_t* wqt   = (ushort_t*)wbase;
    ushort_t* wpt_h = (ushort_t*)(wbase + 576 * 192 * 2);
    ushort_t* wpt_l = (ushort_t*)(wbase + 576 * 192 * 2 + 192 * 192 * 2);
    ushort_t* vT    = (ushort_t*)(wbase + 576 * 192 * 2 + 2 * 192 * 192 * 2);

    convert_x_kernel<<<(NPIX * C_ / 4 + 255) / 256, 256, 0, stream>>>(
        x, xh, NPIX * C_ / 4);
    convert_w_kernel<<<(576 * 192 + 192 * 192 + 255) / 256, 256, 0, stream>>>(
        w_qkv, w_proj, wqt, wpt_h, wpt_l);

    // 1) qkv = x @ w_qkv + b_qkv (bf16 out) + transposed v copy (vT)
    gemm_mfma2_kernel<false, true, true><<<(NPIX / 64) * (QKVC / 192), 256, 0, stream>>>(
        xh, wqt, nullptr, b_qkv, qkvh, vT, NPIX, QKVC, C_);

    // 2) neighborhood attention (MFMA): (g,h,b,i) blocks
    na2d_kernel<<<2304, 384, 0, stream>>>(qkvh, vT, attn);

    // 3) out = attn @ w_proj + b_proj (A bf16, B split-bf16 2-pass)
    gemm_mfma2_kernel<true, false, false><<<(NPIX / 64) * (C_ / 192), 256, 0, stream>>>(
        attn, wpt_h, wpt_l, b_proj, out, nullptr, NPIX, C_, C_);
}